// Round 7
// baseline (74.785 us; speedup 1.0000x reference)
//
#include <hip/hip_runtime.h>
#include <hip/hip_bf16.h>
#include <stdint.h>

// ElementReadoutMLP: species-routed 2-layer MLP, fused.
// Deterministic pipeline (no atomics, no memset):
//   bhist_k / scan_k / dscatter_k : countsort atoms by species (ballot-based)
//   convw_k : W1 [e][k][n] fp32 -> wt, PRE-SWIZZLED k-chunked bf16 layout
//   gemm_k  : PERSISTENT grouped GEMM, 256 blocks x 512 thr (1/CU).
//             Block's atom indices cached in LDS (so the K-loop has ZERO
//             global vector loads -> no compiler vmcnt drains).  A staged
//             fp32 via global_load_lds, 3-deep, counted vmcnt(10) barriers
//             (T4: prefetch DMA never drained).  B slice (32 cols x 256 k
//             = 64 VGPRs) persistent across tiles, reloaded only on species
//             change (~1x/block).  Fused bias+SiLU+W2-dot epilogue.

#define NDIM 256
#define CHUNKS 16      // scan chunks per species (NE*CHUNKS <= 256)
#define BCHUNK 16384   // bytes per B k-chunk (256 n x 32 k x 2B)
#define TROWS 32       // atoms per tile
#define ROWB 1040      // A row pitch bytes (260 dw -> b128 reads conflict-free)
#define MAXT 16        // max tiles per block (atom table sizing)

typedef __attribute__((ext_vector_type(8))) short short8;
typedef __attribute__((ext_vector_type(8))) unsigned short ushort8;
typedef __attribute__((ext_vector_type(4))) float f32x4;

__device__ __forceinline__ unsigned short f2bf(float f) {
  unsigned u = __float_as_uint(f);
  u = (u + 0x7FFFu + ((u >> 16) & 1u)) >> 16;   // round-to-nearest-even
  return (unsigned short)u;
}

// async global->LDS, 16B per lane; lds dest must be wave-uniform base.
__device__ __forceinline__ void gload_lds16(const void* gsrc, void* ldst) {
  __builtin_amdgcn_global_load_lds(
      (const __attribute__((address_space(1))) unsigned*)gsrc,
      (__attribute__((address_space(3))) unsigned*)(uintptr_t)(unsigned)(uintptr_t)ldst,
      16, 0, 0);
}

// pack 8 fp32 -> short8 of bf16 (RNE, packed cvt)
__device__ __forceinline__ short8 cvt8(float4 lo, float4 hi) {
  union { short8 s; unsigned u[4]; } r;
  __hip_bfloat162 t;
  t = __float22bfloat162_rn(make_float2(lo.x, lo.y)); r.u[0] = *(unsigned*)&t;
  t = __float22bfloat162_rn(make_float2(lo.z, lo.w)); r.u[1] = *(unsigned*)&t;
  t = __float22bfloat162_rn(make_float2(hi.x, hi.y)); r.u[2] = *(unsigned*)&t;
  t = __float22bfloat162_rn(make_float2(hi.z, hi.w)); r.u[3] = *(unsigned*)&t;
  return r.s;
}

// ---- prep kernels -----------------------------------------------------------

// wt layout: chunk(e,step) = wt + (e*8+step)*BCHUNK bytes; within chunk,
// bf16 for (n,kk) at byte ((n*64 + kk*2) ^ ((n&7)<<4)).
__global__ void convw_k(const float* __restrict__ W1, unsigned short* __restrict__ wt, int NE) {
  int t = blockIdx.x * 256 + threadIdx.x;          // ((e*8+step)*4 + g)*256 + n
  if (t >= NE * 8192) return;
  int n = t & 255;
  int g = (t >> 8) & 3;            // kk-group of 8
  int step = (t >> 10) & 7;
  int e = t >> 13;
  int k0 = step * 32 + g * 8;
  const float* src = W1 + ((size_t)e << 16) + (size_t)k0 * NDIM + n;  // stride NDIM over j
  unsigned short v[8];
  #pragma unroll
  for (int j = 0; j < 8; ++j) v[j] = f2bf(src[j * NDIM]);
  char* chunk = (char*)wt + (size_t)(e * 8 + step) * BCHUNK;
  unsigned off = ((unsigned)(n * 64 + g * 16)) ^ ((unsigned)((n & 7) << 4));
  *(ushort8*)(chunk + off) = *(ushort8*)v;
}

// per-block histogram, deterministic (ballot-based, no atomics)
__global__ void bhist_k(const int* __restrict__ sp, int n, int* __restrict__ bc, int NE) {
  __shared__ int wc[4][16];
  int tid = threadIdx.x;
  int i = blockIdx.x * 256 + tid;
  int s = (i < n) ? sp[i] : -1;
  int w = tid >> 6, lane = tid & 63;
  for (int e = 0; e < NE; ++e) {
    unsigned long long m = __ballot(s == e);
    if (lane == 0) wc[w][e] = __popcll(m);
  }
  __syncthreads();
  if (tid < NE) bc[blockIdx.x * NE + tid] = wc[0][tid] + wc[1][tid] + wc[2][tid] + wc[3][tid];
}

// deterministic scan: blockCounts -> absolute blockOffs, atom_start, tile_off
__global__ void scan_k(const int* __restrict__ bc, int* __restrict__ bo,
                       int* __restrict__ atom_start, int* __restrict__ tile_off,
                       int nblocks, int NE) {
  __shared__ int csum[256];
  __shared__ int coff[256];
  __shared__ int stot[16];
  __shared__ int sbase[16];
  int tid = threadIdx.x;
  int per = (nblocks + CHUNKS - 1) / CHUNKS;
  int e = tid / CHUNKS, c = tid % CHUNKS;
  int b0 = c * per, b1 = b0 + per; if (b1 > nblocks) b1 = nblocks;
  if (tid < NE * CHUNKS) {
    int s = 0;
    for (int b = b0; b < b1; ++b) s += bc[b * NE + e];
    csum[tid] = s;
  }
  __syncthreads();
  if (tid < NE) {
    int r = 0;
    for (int c2 = 0; c2 < CHUNKS; ++c2) { coff[tid * CHUNKS + c2] = r; r += csum[tid * CHUNKS + c2]; }
    stot[tid] = r;
  }
  __syncthreads();
  if (tid == 0) {
    int a = 0, t = 0;
    for (int e2 = 0; e2 < NE; ++e2) {
      sbase[e2] = a;
      atom_start[e2] = a; tile_off[e2] = t;
      a += stot[e2]; t += (stot[e2] + TROWS - 1) / TROWS;
    }
    atom_start[NE] = a; tile_off[NE] = t;
  }
  __syncthreads();
  if (tid < NE * CHUNKS) {
    int run = sbase[e] + coff[tid];
    for (int b = b0; b < b1; ++b) { bo[b * NE + e] = run; run += bc[b * NE + e]; }
  }
}

// deterministic scatter: rank = block-offset + wave-prefix + lane-prefix
__global__ void dscatter_k(const int* __restrict__ sp, int n, const int* __restrict__ bo,
                           int* __restrict__ sorted, int NE) {
  __shared__ int wc[4][16];
  int tid = threadIdx.x;
  int i = blockIdx.x * 256 + tid;
  int s = (i < n) ? sp[i] : -1;
  int w = tid >> 6, lane = tid & 63;
  for (int e = 0; e < NE; ++e) {
    unsigned long long m = __ballot(s == e);
    if (lane == 0) wc[w][e] = __popcll(m);
  }
  __syncthreads();
  for (int e = 0; e < NE; ++e) {
    unsigned long long m = __ballot(s == e);
    if (s == e) {
      int wpre = 0;
      for (int w2 = 0; w2 < 4; ++w2) if (w2 < w) wpre += wc[w2][e];
      int rank = __popcll(m & ((1ull << lane) - 1ull));
      sorted[bo[blockIdx.x * NE + e] + wpre + rank] = i;
    }
  }
}

// ---- persistent fused grouped GEMM + SiLU + layer2 --------------------------

__global__ __launch_bounds__(512, 2) void gemm_k(
    const float* __restrict__ x, const unsigned short* __restrict__ wt,
    const float* __restrict__ b1, const float* __restrict__ w2,
    const float* __restrict__ b2, const int* __restrict__ sorted,
    const int* __restrict__ atom_start, const int* __restrict__ tile_off,
    float* __restrict__ out, int NE)
{
  // LDS: A triple buffer 3 x 32 x 1040B = 99840 B, atom table, partials,
  // species tables.  ~103 KB -> 1 block/CU (8 waves, VGPR cap 256: no spill).
  __shared__ __align__(16) char ldsA[3][TROWS * ROWB];
  __shared__ float partLds[256];            // 8 waves x 32 rows
  __shared__ int ldsAtoms[MAXT * TROWS];    // block's atom indices (clamped)
  __shared__ int toffs[17], astart[17];

  int tid = threadIdx.x, lane = tid & 63, wid = tid >> 6;   // wid 0..7
  int lr = lane & 15, lg = lane >> 4;

  if (tid <= NE) { toffs[tid] = tile_off[tid]; astart[tid] = atom_start[tid]; }
  __syncthreads();

  int ntiles = toffs[NE];
  int nb = gridDim.x, b = blockIdx.x;
  int q = ntiles / nb, rem = ntiles % nb;
  int t0 = b * q + (b < rem ? b : rem);
  int cnt = q + (b < rem ? 1 : 0);
  if (cnt <= 0) return;
  if (cnt > MAXT) cnt = MAXT;   // safety (not hit at these sizes)
  int t1 = t0 + cnt;

  // ---- cache this block's atom indices in LDS (rows clamped so partial
  // tiles duplicate the last valid row -> benign duplicate out-writes) ----
  for (int i = tid; i < cnt * TROWS; i += 512) {
    int tt = t0 + i / TROWS, r = i % TROWS;
    int e = 0;
    while (tt >= toffs[e + 1]) ++e;
    int rs = astart[e] + (tt - toffs[e]) * TROWS;
    int rv = astart[e + 1] - rs; if (rv > TROWS) rv = TROWS;
    ldsAtoms[i] = sorted[rs + (r < rv ? r : rv - 1)];
  }
  __syncthreads();

  // stage: 4 rows/wave via global_load_lds; indices come from LDS (lgkm only)
  auto stageA = [&](int t, int buf) {
    int base = (t - t0) * TROWS;
    #pragma unroll
    for (int i = 0; i < 4; ++i) {
      int rrow = wid * 4 + i;
      int atom = ldsAtoms[base + rrow];
      gload_lds16(x + (size_t)atom * NDIM + lane * 4, &ldsA[buf][rrow * ROWB]);
    }
  };

  int held_e = -1;
  short8 bf[2][8];          // wave's B slice: 32 cols x 256 k (64 VGPRs, live)
  float bbv[2], wvv[2], b2v = 0.f;

  // prologue: 2 tiles in flight
  stageA(t0, 0);
  stageA(t0 + 1 < t1 ? t0 + 1 : t1 - 1, 1);

  for (int t = t0; t < t1; ++t) {
    int buf = (t - t0) % 3;
    int e = 0;
    while (t >= toffs[e + 1]) ++e;

    // always issue exactly 4 stage loads (dummy re-stage at tail keeps the
    // vmcnt issue-count invariant)
    int ts = t + 2 < t1 ? t + 2 : t1 - 1;
    stageA(ts, (t - t0 + 2) % 3);

    if (e != held_e) {        // ~once per block: load B slice + layer params
      held_e = e;
      const char* wbase = (const char*)wt + (size_t)e * 8 * BCHUNK;
      #pragma unroll
      for (int nf = 0; nf < 2; ++nf) {
        int ncol = wid * 32 + nf * 16 + lr;
        unsigned off = ((unsigned)(ncol * 64 + lg * 16)) ^ ((unsigned)((ncol & 7) << 4));
        #pragma unroll
        for (int s = 0; s < 8; ++s)
          bf[nf][s] = *(const short8*)(wbase + (size_t)s * BCHUNK + off);
        bbv[nf] = b1[(size_t)e * NDIM + ncol];
        wvv[nf] = w2[(size_t)e * NDIM + ncol];
      }
      b2v = b2[e];
    }

    // barrier1 (T4): counted vmcnt -- waits ONLY tile t's 4 loads; the
    // 2-tiles-ahead DMA (8 loads) + last 2 out-stores stay in flight.
    if (t == t0)            { asm volatile("s_waitcnt vmcnt(8)" ::: "memory"); }
    else if (t == t0 + 1)   { asm volatile("s_waitcnt vmcnt(9)" ::: "memory"); }
    else                    { asm volatile("s_waitcnt vmcnt(10)" ::: "memory"); }
    __builtin_amdgcn_s_barrier();
    __builtin_amdgcn_sched_barrier(0);

    // ---- compute: 8 K-steps, no barriers, no global vector loads ----
    f32x4 acc[2][2];
    const f32x4 zero = {0.f, 0.f, 0.f, 0.f};
    #pragma unroll
    for (int i = 0; i < 2; ++i)
      #pragma unroll
      for (int j = 0; j < 2; ++j) acc[i][j] = zero;

    const char* Ab = ldsA[buf];
    #pragma unroll
    for (int step = 0; step < 8; ++step) {
      int k0 = step * 32;
      short8 af[2];
      #pragma unroll
      for (int mf = 0; mf < 2; ++mf) {
        const char* p = Ab + (mf * 16 + lr) * ROWB + (k0 + lg * 8) * 4;
        float4 lo = *(const float4*)p;
        float4 hi = *(const float4*)(p + 16);
        af[mf] = cvt8(lo, hi);
      }
      #pragma unroll
      for (int mf = 0; mf < 2; ++mf)
        #pragma unroll
        for (int nf = 0; nf < 2; ++nf)
          acc[mf][nf] = __builtin_amdgcn_mfma_f32_16x16x32_bf16(af[mf], bf[nf][step], acc[mf][nf], 0, 0, 0);
    }

    // ---- epilogue: +b1, SiLU, dot W2, reduce ----
    float psum[2][4];
    #pragma unroll
    for (int mf = 0; mf < 2; ++mf)
      #pragma unroll
      for (int rg = 0; rg < 4; ++rg) psum[mf][rg] = 0.f;

    #pragma unroll
    for (int nf = 0; nf < 2; ++nf) {
      #pragma unroll
      for (int mf = 0; mf < 2; ++mf)
        #pragma unroll
        for (int rg = 0; rg < 4; ++rg) {
          float h = acc[mf][nf][rg] + bbv[nf];
          float sv = h * __builtin_amdgcn_rcpf(1.f + __expf(-h));   // SiLU
          psum[mf][rg] += sv * wvv[nf];
        }
    }
    #pragma unroll
    for (int mf = 0; mf < 2; ++mf)
      #pragma unroll
      for (int rg = 0; rg < 4; ++rg) {
        float v = psum[mf][rg];
        v += __shfl_xor(v, 1, 64);
        v += __shfl_xor(v, 2, 64);
        v += __shfl_xor(v, 4, 64);
        v += __shfl_xor(v, 8, 64);
        psum[mf][rg] = v;
      }
    if (lr == 0) {
      #pragma unroll
      for (int mf = 0; mf < 2; ++mf)
        #pragma unroll
        for (int rg = 0; rg < 4; ++rg)
          partLds[wid * TROWS + mf * 16 + lg * 4 + rg] = psum[mf][rg];
    }

    // barrier2: LDS-only (lgkmcnt) -- prefetch DMA stays in flight.
    asm volatile("s_waitcnt lgkmcnt(0)" ::: "memory");
    __builtin_amdgcn_s_barrier();
    __builtin_amdgcn_sched_barrier(0);

    if (tid < TROWS) {
      float s = b2v;
      #pragma unroll
      for (int w = 0; w < 8; ++w) s += partLds[w * TROWS + tid];
      out[ldsAtoms[(t - t0) * TROWS + tid]] = s;   // index via LDS: no vmcnt
    }
  }
}

// ---- launch -----------------------------------------------------------------

extern "C" void kernel_launch(void* const* d_in, const int* in_sizes, int n_in,
                              void* d_out, int out_size, void* d_ws, size_t ws_size,
                              hipStream_t stream) {
  const float* x  = (const float*)d_in[0];
  const int*   sp = (const int*)d_in[1];
  const float* W1 = (const float*)d_in[2];
  const float* b1 = (const float*)d_in[3];
  const float* W2 = (const float*)d_in[4];
  const float* b2 = (const float*)d_in[5];
  float* out = (float*)d_out;

  int n_atoms = in_sizes[0] / NDIM;
  int NE = in_sizes[2] / (NDIM * NDIM);
  int nblocks = (n_atoms + 255) / 256;

  // workspace layout (all 256-aligned); every word read is written this call.
  char* wsb = (char*)d_ws;
  size_t o = 0;
  int* bc = (int*)(wsb + o);         o += ((size_t)nblocks * NE * 4 + 255) & ~(size_t)255;
  int* bo = (int*)(wsb + o);         o += ((size_t)nblocks * NE * 4 + 255) & ~(size_t)255;
  int* atom_start = (int*)(wsb + o); o += 256;
  int* tile_off   = (int*)(wsb + o); o += 256;
  int* sorted     = (int*)(wsb + o); o += ((size_t)n_atoms * 4 + 255) & ~(size_t)255;
  unsigned short* wt = (unsigned short*)(wsb + o);   // NE*128KB, 256-aligned

  hipLaunchKernelGGL(convw_k, dim3((NE * 8192 + 255) / 256), dim3(256), 0, stream,
                     W1, wt, NE);
  hipLaunchKernelGGL(bhist_k, dim3(nblocks), dim3(256), 0, stream, sp, n_atoms, bc, NE);
  hipLaunchKernelGGL(scan_k, dim3(1), dim3(256), 0, stream, bc, bo, atom_start, tile_off,
                     nblocks, NE);
  hipLaunchKernelGGL(dscatter_k, dim3(nblocks), dim3(256), 0, stream, sp, n_atoms, bo,
                     sorted, NE);

  hipLaunchKernelGGL(gemm_k, dim3(256), dim3(512), 0, stream,
                     x, wt, b1, W2, b2, sorted, atom_start, tile_off, out, NE);
}